// Round 5
// baseline (15.677 us; speedup 1.0000x reference)
//
#include <hip/hip_runtime.h>

// votes[b,n,m,o] = sum_i inputs[b,n,i] * W[n,m,i,o]
// B=64, N_IN=1152, N_OUT=10, D_IN=8, D_OUT=16
// Round 2: XCD-swizzle so all 8 batch-replicas of a (n,m,o4) chunk share one
// XCD's L2 (W footprint/XCD: 5.9MB -> 0.74MB). Round 4 A/B: drop the
// non-temporal store — fills hit 6.4 TB/s with plain stores, and the swizzle
// alone keeps W L2-resident (0.74MB of 4MiB); nt may defeat write-combining.

typedef float floatx4 __attribute__((ext_vector_type(4)));

constexpr int B     = 64;
constexpr int N_IN  = 1152;
constexpr int N_OUT = 10;
constexpr int D_IN  = 8;
constexpr int D_OUT = 16;
constexpr int KB    = 8;                       // b values per thread
constexpr int NCHUNK = N_IN * N_OUT * 4 / 256; // 180 chunks of 256 threads
constexpr int NBLOCKS = NCHUNK * (B / KB);     // 1440

__global__ __launch_bounds__(256)
void Transforming_56195352101061_kernel(const float* __restrict__ in,
                                        const float* __restrict__ W,
                                        float* __restrict__ out) {
    // Swizzle: blockIdx.x -> (bb, c) such that blockIdx.x % 8 is a function
    // of c only (for the first 1408 blocks). All 8 bb-replicas of chunk c
    // then land on the same XCD (assuming xcd = dispatch_order % 8).
    int id = blockIdx.x;
    int bb, c;
    if (id < 1408) {                 // 8 r * 8 bb * 22 g
        int r = id & 7;
        int t = id >> 3;
        bb    = t & 7;
        c     = (t >> 3) * 8 + r;    // c = 8g + r, g in [0,22)
    } else {                         // tail: c in [176,180), 2% of blocks
        int k = id - 1408;
        bb    = k >> 2;
        c     = 176 + (k & 3);
    }

    int tid = c * 256 + (int)threadIdx.x;   // [0, 46080) over (n,m,o4)
    int o4  = tid & 3;
    int lin = tid >> 2;
    int m   = lin % N_OUT;
    int n   = lin / N_OUT;

    // Load this thread's W column once: 8 float4s (one per i). L2-resident.
    const float* wbase = W + ((size_t)(n * N_OUT + m) * D_IN) * D_OUT + o4 * 4;
    floatx4 w[D_IN];
#pragma unroll
    for (int i = 0; i < D_IN; ++i)
        w[i] = *reinterpret_cast<const floatx4*>(wbase + i * D_OUT);

    const float* ibase = in + ((size_t)(bb * KB) * N_IN + n) * D_IN;
    floatx4* out4 = reinterpret_cast<floatx4*>(out);

#pragma unroll
    for (int j = 0; j < KB; ++j) {
        int b = bb * KB + j;
        const floatx4* iv = reinterpret_cast<const floatx4*>(
            ibase + (size_t)j * N_IN * D_IN);
        floatx4 i0 = iv[0];
        floatx4 i1 = iv[1];
        float ivals[8] = {i0.x, i0.y, i0.z, i0.w, i1.x, i1.y, i1.z, i1.w};

        floatx4 acc = {0.f, 0.f, 0.f, 0.f};
#pragma unroll
        for (int i = 0; i < D_IN; ++i) {
            acc += ivals[i] * w[i];
        }

        // Plain store: full-line coalesced, L2 write-combined.
        out4[((size_t)(b * N_IN + n) * N_OUT + m) * 4 + o4] = acc;
    }
}

extern "C" void kernel_launch(void* const* d_in, const int* in_sizes, int n_in,
                              void* d_out, int out_size, void* d_ws, size_t ws_size,
                              hipStream_t stream) {
    const float* in = (const float*)d_in[0];   // [B, N_IN, 8, 1]
    const float* W  = (const float*)d_in[1];   // [1, N_IN, N_OUT, 8, 16, 1]
    float* out      = (float*)d_out;           // [B, N_IN, N_OUT, 16, 1]

    Transforming_56195352101061_kernel<<<NBLOCKS, 256, 0, stream>>>(in, W, out);
}

// Round 6
// 14.221 us; speedup vs baseline: 1.1024x; 1.1024x over previous
//
#include <hip/hip_runtime.h>

// votes[b,n,m,o] = sum_i inputs[b,n,i] * W[n,m,i,o]
// B=64, N_IN=1152, N_OUT=10, D_IN=8, D_OUT=16
// R4/R5 A/B: nt-store = 1.6us win (write stream thrashed L2); swizzle alone
// neutral. R6: KB=16 halves W request amplification (47->23.6 MB) while
// keeping 2880 waves (enough TLP). nt stores + 4-replica XCD swizzle kept.

typedef float floatx4 __attribute__((ext_vector_type(4)));

constexpr int B     = 64;
constexpr int N_IN  = 1152;
constexpr int N_OUT = 10;
constexpr int D_IN  = 8;
constexpr int D_OUT = 16;
constexpr int KB    = 16;                      // b values per thread
constexpr int NBB   = B / KB;                  // 4 batch groups
constexpr int NCHUNK = N_IN * N_OUT * 4 / 256; // 180 chunks of 256 threads
constexpr int NBLOCKS = NCHUNK * NBB;          // 720
constexpr int MAIN  = 176 * NBB;               // 704 swizzled blocks

__global__ __launch_bounds__(256)
void Transforming_56195352101061_kernel(const float* __restrict__ in,
                                        const float* __restrict__ W,
                                        float* __restrict__ out) {
    // Swizzle: all NBB batch-replicas of chunk c satisfy blockIdx%8 == c%8,
    // so they share one XCD's L2 (assuming xcd = dispatch_order % 8).
    int id = blockIdx.x;
    int bb, c;
    if (id < MAIN) {                 // id = 32g + 8*bb + r,  c = 8g + r
        int r = id & 7;
        int t = id >> 3;
        bb    = t & 3;
        c     = (t >> 2) * 8 + r;    // g in [0,22)
    } else {                         // tail: c in [176,180)
        int k = id - MAIN;
        bb    = k >> 2;
        c     = 176 + (k & 3);
    }

    int tid = c * 256 + (int)threadIdx.x;   // [0, 46080) over (n,m,o4)
    int o4  = tid & 3;
    int lin = tid >> 2;
    int m   = lin % N_OUT;
    int n   = lin / N_OUT;

    // Load this thread's W column once: 8 float4s (one per i).
    const float* wbase = W + ((size_t)(n * N_OUT + m) * D_IN) * D_OUT + o4 * 4;
    floatx4 w[D_IN];
#pragma unroll
    for (int i = 0; i < D_IN; ++i)
        w[i] = *reinterpret_cast<const floatx4*>(wbase + i * D_OUT);

    const float* ibase = in + ((size_t)(bb * KB) * N_IN + n) * D_IN;
    floatx4* out4 = reinterpret_cast<floatx4*>(out);
    size_t obase = ((size_t)((bb * KB) * N_IN + n) * N_OUT + m) * 4 + o4;
    constexpr size_t OB_STRIDE = (size_t)N_IN * N_OUT * 4;  // float4s per b

#pragma unroll 4
    for (int j = 0; j < KB; ++j) {
        const floatx4* iv = reinterpret_cast<const floatx4*>(
            ibase + (size_t)j * N_IN * D_IN);
        floatx4 i0 = iv[0];
        floatx4 i1 = iv[1];
        float ivals[8] = {i0.x, i0.y, i0.z, i0.w, i1.x, i1.y, i1.z, i1.w};

        floatx4 acc = {0.f, 0.f, 0.f, 0.f};
#pragma unroll
        for (int i = 0; i < D_IN; ++i)
            acc += ivals[i] * w[i];

        __builtin_nontemporal_store(acc, &out4[obase + (size_t)j * OB_STRIDE]);
    }
}

extern "C" void kernel_launch(void* const* d_in, const int* in_sizes, int n_in,
                              void* d_out, int out_size, void* d_ws, size_t ws_size,
                              hipStream_t stream) {
    const float* in = (const float*)d_in[0];   // [B, N_IN, 8, 1]
    const float* W  = (const float*)d_in[1];   // [1, N_IN, N_OUT, 8, 16, 1]
    float* out      = (float*)d_out;           // [B, N_IN, N_OUT, 16, 1]

    Transforming_56195352101061_kernel<<<NBLOCKS, 256, 0, stream>>>(in, W, out);
}